// Round 1
// baseline (84.271 us; speedup 1.0000x reference)
//
#include <hip/hip_runtime.h>

// YOLOv3 layer = per-batch 255x2704 transpose + per-channel elementwise map.
//   out[b][hw][c] = f_c(in[b][c][hw]),  c = a*85 + d
//   d==0: (sigmoid(x)+w)/52   (w = hw%52)
//   d==1: (sigmoid(x)+h)/52   (h = hw/52)
//   d==2: (aw[a]/416)*exp(x)
//   d==3: (ah[a]/416)*exp(x)
//   d>=4: sigmoid(x)
// plus trailing scalar out[64*689520] = -1.0f

#define CH    255
#define HWTOT 2704
#define NB    64
#define WDIM  52
#define BOX   85
#define PER_B (CH * HWTOT)   // 689520

__device__ __forceinline__ float fast_sigmoid(float x) {
    // rcp(1 + exp(-x)); v_exp_f32 + v_rcp_f32, ~1 ulp each — far under threshold
    return __builtin_amdgcn_rcpf(1.0f + __expf(-x));
}

__global__ __launch_bounds__(256) void yolo_kernel(const float* __restrict__ in,
                                                   float* __restrict__ out) {
    __shared__ float tile[64][65];   // +1 pad: stride 65 == 1 mod 32 -> conflict-free

    const int t   = threadIdx.x;
    const int hw0 = blockIdx.x * 64;     // 43 tiles over 2704
    const int c0  = blockIdx.y * 64;     // 4 tiles over 255
    const int b   = blockIdx.z;

    const float* inb = in + (size_t)b * PER_B;

    // ---- load phase: float4 coalesced along hw, apply f, store to LDS ----
    const int col4 = (t & 15) * 4;       // 0..60
    const int r0   = t >> 4;             // 0..15
    #pragma unroll
    for (int i = 0; i < 4; ++i) {
        const int r   = r0 + i * 16;     // 0..63 (c-tile row)
        const int c   = c0 + r;
        const int hwc = hw0 + col4;
        if (c < CH && hwc < HWTOT) {     // hwc%4==0 and HWTOT%4==0 -> no straddle
            const float4 v = *reinterpret_cast<const float4*>(inb + (size_t)c * HWTOT + hwc);
            const int d = c % BOX;
            const int a = c / BOX;
            const float vv[4] = {v.x, v.y, v.z, v.w};
            float res[4];
            #pragma unroll
            for (int j = 0; j < 4; ++j) {
                const float x = vv[j];
                float o;
                if (d == 2) {
                    const float s = (a == 0) ? (10.0f/416.0f) : (a == 1) ? (16.0f/416.0f) : (33.0f/416.0f);
                    o = s * __expf(x);
                } else if (d == 3) {
                    const float s = (a == 0) ? (13.0f/416.0f) : (a == 1) ? (30.0f/416.0f) : (23.0f/416.0f);
                    o = s * __expf(x);
                } else {
                    const float sg = fast_sigmoid(x);
                    if (d == 0) {
                        const int w = (hwc + j) % WDIM;
                        o = (sg + (float)w) * (1.0f / 52.0f);
                    } else if (d == 1) {
                        const int h = (hwc + j) / WDIM;
                        o = (sg + (float)h) * (1.0f / 52.0f);
                    } else {
                        o = sg;
                    }
                }
                res[j] = o;
            }
            tile[r][col4 + 0] = res[0];
            tile[r][col4 + 1] = res[1];
            tile[r][col4 + 2] = res[2];
            tile[r][col4 + 3] = res[3];
        }
    }

    __syncthreads();

    // ---- store phase: coalesced along c ----
    const int cc = t & 63;               // c offset within tile
    const int rb = t >> 6;               // 0..3
    const int c  = c0 + cc;
    if (c < CH) {
        float* outb = out + (size_t)b * PER_B;
        #pragma unroll
        for (int i = 0; i < 16; ++i) {
            const int r  = rb + i * 4;
            const int hw = hw0 + r;
            if (hw < HWTOT)
                outb[(size_t)hw * CH + c] = tile[cc][r];   // lanes vary cc -> 256B runs
        }
    }

    if (t == 0 && blockIdx.x == 0 && blockIdx.y == 0 && blockIdx.z == 0)
        out[(size_t)NB * PER_B] = -1.0f;   // trailing scalar output
}

extern "C" void kernel_launch(void* const* d_in, const int* in_sizes, int n_in,
                              void* d_out, int out_size, void* d_ws, size_t ws_size,
                              hipStream_t stream) {
    const float* x = (const float*)d_in[0];
    float* out = (float*)d_out;
    dim3 grid((HWTOT + 63) / 64, (CH + 63) / 64, NB);   // 43 x 4 x 64
    yolo_kernel<<<grid, dim3(256), 0, stream>>>(x, out);
}

// Round 2
// 81.283 us; speedup vs baseline: 1.0368x; 1.0368x over previous
//
#include <hip/hip_runtime.h>

// YOLOv3 layer = per-batch 255x2704 transpose + per-channel elementwise map.
//   out[b][hw][c] = f_c(in[b][c][hw]),  c = a*85 + d
//   d==0: (sigmoid(x)+w)/52   (w = hw%52)
//   d==1: (sigmoid(x)+h)/52   (h = hw/52)
//   d==2: (aw[a]/416)*exp(x)
//   d==3: (ah[a]/416)*exp(x)
//   d>=4: sigmoid(x)
// plus trailing scalar out[64*689520] = -1.0f
//
// Block geometry: 16 hw-rows x all 255 channels -> output span is 4080
// contiguous floats (16320 B, 16B-aligned base) => store phase is a linear
// float4 LDS->global copy: dense, aligned, no partial-line RMW.

#define CH    255
#define HWTOT 2704
#define NB    64
#define WDIM  52
#define BOX   85
#define PER_B (CH * HWTOT)   // 689520
#define HWROWS 16
#define HWBLKS (HWTOT / HWROWS)   // 169

__device__ __forceinline__ float fast_sigmoid(float x) {
    return __builtin_amdgcn_rcpf(1.0f + __expf(-x));
}

__global__ __launch_bounds__(256) void yolo_kernel(const float* __restrict__ in,
                                                   float* __restrict__ out) {
    __shared__ float tile[HWROWS * CH];   // dense: tile[hwl*255 + c], 16320 B

    const int t     = threadIdx.x;
    const int bid   = blockIdx.x;
    const int hwblk = bid % HWBLKS;
    const int b     = bid / HWBLKS;
    const int hw0   = hwblk * HWROWS;

    const float* inb = in + (size_t)b * PER_B;

    // ---- load: float4 along hw (64B, line-aligned), apply f, scatter to LDS ----
    const int col = (t & 3) * 4;          // hw offset within 16-row stripe
    const int cbase = t >> 2;             // 0..63
    #pragma unroll
    for (int i = 0; i < 4; ++i) {
        const int c = cbase + 64 * i;     // 0..255
        if (c < CH) {
            const float4 v = *reinterpret_cast<const float4*>(
                inb + (size_t)c * HWTOT + hw0 + col);
            const int d = c % BOX;
            const int a = c / BOX;
            const float vv[4] = {v.x, v.y, v.z, v.w};
            #pragma unroll
            for (int j = 0; j < 4; ++j) {
                const float x = vv[j];
                float o;
                if (d == 2) {
                    const float s = (a == 0) ? (10.0f/416.0f) : (a == 1) ? (16.0f/416.0f) : (33.0f/416.0f);
                    o = s * __expf(x);
                } else if (d == 3) {
                    const float s = (a == 0) ? (13.0f/416.0f) : (a == 1) ? (30.0f/416.0f) : (23.0f/416.0f);
                    o = s * __expf(x);
                } else {
                    const float sg = fast_sigmoid(x);
                    if (d == 0) {
                        const int w = (hw0 + col + j) % WDIM;
                        o = (sg + (float)w) * (1.0f / 52.0f);
                    } else if (d == 1) {
                        const int h = (hw0 + col + j) / WDIM;
                        o = (sg + (float)h) * (1.0f / 52.0f);
                    } else {
                        o = sg;
                    }
                }
                tile[(col + j) * CH + c] = o;
            }
        }
    }

    __syncthreads();

    // ---- store: linear float4 copy, perfectly coalesced + aligned ----
    const float4* t4 = reinterpret_cast<const float4*>(tile);
    float4* o4 = reinterpret_cast<float4*>(out + (size_t)b * PER_B + (size_t)hw0 * CH);
    #pragma unroll
    for (int i = 0; i < 4; ++i) {
        const int idx = t + 256 * i;      // 0..1019 of 1020 float4s
        if (idx < (HWROWS * CH) / 4)
            o4[idx] = t4[idx];
    }

    if (t == 0 && bid == 0)
        out[(size_t)NB * PER_B] = -1.0f;  // trailing scalar output
}

extern "C" void kernel_launch(void* const* d_in, const int* in_sizes, int n_in,
                              void* d_out, int out_size, void* d_ws, size_t ws_size,
                              hipStream_t stream) {
    const float* x = (const float*)d_in[0];
    float* out = (float*)d_out;
    yolo_kernel<<<dim3(HWBLKS * NB), dim3(256), 0, stream>>>(x, out);
}

// Round 4
// 79.836 us; speedup vs baseline: 1.0556x; 1.0181x over previous
//
#include <hip/hip_runtime.h>

// YOLOv3 layer = per-batch 255x2704 transpose + per-channel elementwise map.
//   out[b][hw][c] = f_c(in[b][c][hw]),  c = a*85 + d
//   d==0: (sig(x)+w)/52   d==1: (sig(x)+h)/52
//   d==2: (aw[a]/416)*exp(x)   d==3: (ah[a]/416)*exp(x)   d>=4: sig(x)
// plus trailing scalar out[64*689520] = -1.0f
//
// R2 lesson: VGPR=12 => compiler serialized the 4 loads (latency-bound,
// 3.5 TB/s eff. vs 7 TB/s streaming ceiling). This round: batched
// unconditional loads (clamped row), branchless map (one exp serves
// sigmoid e/(1+e) and scale*e), nontemporal stores (via clang native
// vector type — __builtin_nontemporal_store rejects HIP_vector_type).

#define CH    255
#define HWTOT 2704
#define NB    64
#define WDIM  52
#define BOX   85
#define PER_B (CH * HWTOT)   // 689520
#define HWROWS 16
#define HWBLKS (HWTOT / HWROWS)   // 169

typedef float vfloat4 __attribute__((ext_vector_type(4)));

__global__ __launch_bounds__(256) void yolo_kernel(const float* __restrict__ in,
                                                   float* __restrict__ out) {
    __shared__ float tile[HWROWS * CH];   // dense: tile[hwl*255 + c], 16320 B

    const int t     = threadIdx.x;
    const int bid   = blockIdx.x;
    const int hwblk = bid % HWBLKS;
    const int b     = bid / HWBLKS;
    const int hw0   = hwblk * HWROWS;

    const float* inb = in + (size_t)b * PER_B + hw0;

    const int col   = (t & 3) * 4;       // hw offset within stripe
    const int cbase = t >> 2;            // 0..63

    // ---- per-thread j-constants: w/52 and h/52 for the 4 hw positions ----
    float wj[4], hj[4];
    #pragma unroll
    for (int j = 0; j < 4; ++j) {
        const int hwp = hw0 + col + j;
        const float fh = floorf((float)hwp * (1.0f / 52.0f));  // exact: err ~3e-6 << 1/52
        hj[j] = fh * (1.0f / 52.0f);
        wj[j] = ((float)hwp - 52.0f * fh) * (1.0f / 52.0f);
    }

    // ---- batched loads: 4 unconditional global_load_dwordx4, one waitcnt ----
    vfloat4 v[4];
    #pragma unroll
    for (int i = 0; i < 4; ++i) {
        const int c  = cbase + 64 * i;           // 0..255
        const int cl = (c > CH - 1) ? (CH - 1) : c;  // clamp: c==255 loads row 254, discarded
        v[i] = *reinterpret_cast<const vfloat4*>(inb + (size_t)cl * HWTOT + col);
    }

    // ---- branchless elementwise map + LDS scatter ----
    #pragma unroll
    for (int i = 0; i < 4; ++i) {
        const int c = cbase + 64 * i;
        const int a = (c >= 2 * BOX) ? 2 : (c >= BOX ? 1 : 0);
        const int d = c - a * BOX;
        const float sw = (a == 0) ? (10.0f/416.0f) : (a == 1) ? (16.0f/416.0f) : (33.0f/416.0f);
        const float sh = (a == 0) ? (13.0f/416.0f) : (a == 1) ? (30.0f/416.0f) : (23.0f/416.0f);
        const float sc = (d == 2) ? sw : sh;
        const bool is_xy = (d < 2);
        const bool is_wh = (d == 2) || (d == 3);
        if (c < CH) {   // only masks cbase==63,i==3; no loads inside
            #pragma unroll
            for (int j = 0; j < 4; ++j) {
                const float x  = v[i][j];
                const float e  = __expf(x);                       // one exp serves both paths
                const float sg = e * __builtin_amdgcn_rcpf(1.0f + e);  // sigmoid = e/(1+e)
                const float axy = (d == 0) ? wj[j] : hj[j];
                float o = is_xy ? (sg * (1.0f/52.0f) + axy) : sg;
                o = is_wh ? (sc * e) : o;
                tile[(col + j) * CH + c] = o;
            }
        }
    }

    __syncthreads();

    // ---- store: linear float4 copy, nontemporal (don't thrash L3 input) ----
    const vfloat4* t4 = reinterpret_cast<const vfloat4*>(tile);
    vfloat4* o4 = reinterpret_cast<vfloat4*>(out + (size_t)b * PER_B + (size_t)hw0 * CH);
    #pragma unroll
    for (int i = 0; i < 4; ++i) {
        const int idx = t + 256 * i;      // 0..1019 of 1020 float4s
        if (idx < (HWROWS * CH) / 4)
            __builtin_nontemporal_store(t4[idx], &o4[idx]);
    }

    if (t == 0 && bid == 0)
        out[(size_t)NB * PER_B] = -1.0f;  // trailing scalar output
}

extern "C" void kernel_launch(void* const* d_in, const int* in_sizes, int n_in,
                              void* d_out, int out_size, void* d_ws, size_t ws_size,
                              hipStream_t stream) {
    const float* x = (const float*)d_in[0];
    float* out = (float*)d_out;
    yolo_kernel<<<dim3(HWBLKS * NB), dim3(256), 0, stream>>>(x, out);
}

// Round 5
// 73.699 us; speedup vs baseline: 1.1435x; 1.0833x over previous
//
#include <hip/hip_runtime.h>

// YOLOv3 layer = per-batch 255x2704 transpose + per-channel elementwise map.
//   out[b][hw][c] = f_c(in[b][c][hw]),  c = a*85 + d
//   d==0: (sig(x)+w)/52   d==1: (sig(x)+h)/52
//   d==2: (aw[a]/416)*exp(x)   d==3: (ah[a]/416)*exp(x)   d>=4: sig(x)
// plus trailing scalar out[64*689520] = -1.0f
//
// R4 lesson: batched loads only -1.5us (not latency-bound); nt stores RAISED
// FETCH 108->172MB (reverted). At 4.4 TB/s eff = 70% of copy ceiling, the
// suspect is the 64B-granular read gather (stride 10.8KB). This round:
// HWROWS=52 -> 208B contiguous per c-row (3.25x longer runs), h/w indexing
// becomes free (h = block-uniform, w = slot position), plain stores.

#define CH     255
#define HWTOT  2704
#define NB     64
#define BOX    85
#define PER_B  (CH * HWTOT)        // 689520
#define HWROWS 52
#define HWBLKS (HWTOT / HWROWS)    // 52  (== grid rows; hwblk IS h)
#define SLOTS  (CH * (HWROWS/4))   // 3315 float4 slots per tile
#define THREADS 512

typedef float vfloat4 __attribute__((ext_vector_type(4)));

__global__ __launch_bounds__(THREADS) void yolo_kernel(const float* __restrict__ in,
                                                       float* __restrict__ out) {
    __shared__ float tile[HWROWS * CH];   // [w][c], 53040 B

    const int t     = threadIdx.x;
    const int bid   = blockIdx.x;
    const int hwblk = bid % HWBLKS;       // == h (0..51), block-uniform
    const int b     = bid / HWBLKS;
    const int hw0   = hwblk * HWROWS;

    const float* inb  = in + (size_t)b * PER_B + hw0;
    const float hnorm = (float)hwblk * (1.0f / 52.0f);   // h/52

    // ---- load: 7 batched float4 loads; 208B-contiguous run per c-row ----
    vfloat4 v[7];
    int cs[7], gs[7];
    #pragma unroll
    for (int k = 0; k < 7; ++k) {
        const int s   = t + THREADS * k;
        const int scl = (s < SLOTS) ? s : (SLOTS - 1);        // clamp tail
        const int c   = (int)(((unsigned)scl * 20165u) >> 18); // scl/13 (magic, exact for s<2^18)
        const int g   = scl - c * 13;                          // float4 group within row
        cs[k] = c; gs[k] = g;
        v[k] = *reinterpret_cast<const vfloat4*>(inb + (size_t)c * HWTOT + g * 4);
    }

    // ---- branchless transform + LDS scatter ----
    #pragma unroll
    for (int k = 0; k < 7; ++k) {
        const int s = t + THREADS * k;
        const int c = cs[k], g = gs[k];
        const int a = (c >= 2*BOX) ? 2 : (c >= BOX) ? 1 : 0;
        const int d = c - a * BOX;
        const float sw = (a==0) ? (10.0f/416.0f) : (a==1) ? (16.0f/416.0f) : (33.0f/416.0f);
        const float sh = (a==0) ? (13.0f/416.0f) : (a==1) ? (30.0f/416.0f) : (23.0f/416.0f);
        const float sc = (d == 2) ? sw : sh;
        const bool is_xy = (d < 2);
        const bool is_wh = (d == 2) | (d == 3);
        if (s < SLOTS) {
            #pragma unroll
            for (int j = 0; j < 4; ++j) {
                const float x  = v[k][j];
                const float e  = __expf(x);                          // serves both paths
                const float sg = e * __builtin_amdgcn_rcpf(1.0f + e); // sigmoid = e/(1+e)
                const float wn = (float)(g*4 + j) * (1.0f / 52.0f);   // w/52 (w = g*4+j)
                const float axy = (d == 0) ? wn : hnorm;
                float o = is_xy ? (sg * (1.0f/52.0f) + axy) : sg;
                o = is_wh ? (sc * e) : o;
                tile[(g*4 + j) * CH + c] = o;
            }
        }
    }

    __syncthreads();

    // ---- store: linear float4 copy of 53KB contiguous out span ----
    const vfloat4* t4 = reinterpret_cast<const vfloat4*>(tile);
    vfloat4* o4 = reinterpret_cast<vfloat4*>(out + (size_t)b * PER_B + (size_t)hw0 * CH);
    #pragma unroll
    for (int k = 0; k < 7; ++k) {
        const int idx = t + THREADS * k;
        if (idx < SLOTS)
            o4[idx] = t4[idx];
    }

    if (t == 0 && bid == 0)
        out[(size_t)NB * PER_B] = -1.0f;   // trailing scalar output
}

extern "C" void kernel_launch(void* const* d_in, const int* in_sizes, int n_in,
                              void* d_out, int out_size, void* d_ws, size_t ws_size,
                              hipStream_t stream) {
    const float* x = (const float*)d_in[0];
    float* out = (float*)d_out;
    yolo_kernel<<<dim3(HWBLKS * NB), dim3(THREADS), 0, stream>>>(x, out);
}